// Round 13
// baseline (505.347 us; speedup 1.0000x reference)
//
#include <hip/hip_runtime.h>
#include <cstdint>

// MHA fused, SINGLE persistent dispatch with software grid barrier.
// Round-9 measured ~98us of inter-dispatch overhead across 4 launches; round-11
// coop launch silently failed (not graph-capturable). This uses a PLAIN launch
// (capturable) + device-scope atomic barrier; co-residency by construction:
// 64KB LDS -> exactly 2 blocks/CU x 256 CU = 512 = grid.
// Stages: 0) casts q,k,Wq,Wk,Wo -> bf16; 1) gemm_qk (round-9 dbuf mainloop,
// XCD swizzle) z=0,1 per block; 2) flash v2 (round-2 verified body) on
// balanced tile pairs (pj,15-pj) = 34 iters/block; 3) gemm_o.
// B=4 T=2048 E=1024 H=16 D=64. v input (d_in[2]) DEAD (share_kv=True).
// Round-12 single-buffer GEMM REVERTED (dbuf prefetch-overlap > occupancy).

typedef unsigned short u16;
typedef __attribute__((ext_vector_type(8))) short short8;
typedef __attribute__((ext_vector_type(4))) float f32x4;
typedef __attribute__((ext_vector_type(4))) unsigned short u16x4;
typedef __attribute__((ext_vector_type(2))) unsigned int u32x2;

__device__ __forceinline__ u16 f2bf(float x) {
  unsigned int u = __float_as_uint(x);
  u += 0x7fffu + ((u >> 16) & 1u);   // RNE
  return (u16)(u >> 16);
}

__device__ __forceinline__ float fexp2(float x) {
#if __has_builtin(__builtin_amdgcn_exp2f)
  return __builtin_amdgcn_exp2f(x);
#else
  return __expf(x * 0.69314718056f);
#endif
}

__device__ __forceinline__ float frcp(float x) {
#if __has_builtin(__builtin_amdgcn_rcpf)
  return __builtin_amdgcn_rcpf(x);
#else
  return 1.0f / x;
#endif
}

__device__ __forceinline__ void load16_to_lds(const void* g, void* lds_base_uniform) {
  // HW writes LDS at wave-uniform base + lane*16; g is per-lane.
  __builtin_amdgcn_global_load_lds(
      (const __attribute__((address_space(1))) void*)g,
      (__attribute__((address_space(3))) void*)lds_base_uniform,
      16, 0, 0);
}

// pack two f32 -> one dword of 2 truncated bf16 (lo = a, hi = b)
__device__ __forceinline__ unsigned pack_bf16(float a, float b) {
  return __builtin_amdgcn_perm(__float_as_uint(b), __float_as_uint(a), 0x07060302u);
}

// swap halves: {x,y} -> x' = {x.lo32lanes, y.lo32lanes}, y' = {x.hi, y.hi}
__device__ __forceinline__ void plane32_swap(unsigned &x, unsigned &y) {
#if __has_builtin(__builtin_amdgcn_permlane32_swap)
  u32x2 r = __builtin_amdgcn_permlane32_swap(x, y, false, false);
  x = r.x; y = r.y;
#else
  asm volatile("v_permlane32_swap_b32 %0, %1" : "+v"(x), "+v"(y));
#endif
}

__device__ __forceinline__ void plane16_swap(unsigned &x, unsigned &y) {
#if __has_builtin(__builtin_amdgcn_permlane16_swap)
  u32x2 r = __builtin_amdgcn_permlane16_swap(x, y, false, false);
  x = r.x; y = r.y;
#else
  asm volatile("v_permlane16_swap_b32 %0, %1" : "+v"(x), "+v"(y));
#endif
}

__device__ __forceinline__ void cast4(const float* __restrict__ s,
                                      u16* __restrict__ d, int i) {
  float4 f = ((const float4*)s)[i];
  uint2 p;
  p.x = (unsigned int)f2bf(f.x) | ((unsigned int)f2bf(f.y) << 16);
  p.y = (unsigned int)f2bf(f.z) | ((unsigned int)f2bf(f.w) << 16);
  ((uint2*)d)[i] = p;
}

// ---------------- software grid barrier (agent-scope, G16-compliant) ----------------
// All 512 blocks are co-resident (LDS-bound 2/CU x 256 CU). Release on arrival
// (fetch_add ACQ_REL) publishes each block's writes; last block releases gen;
// spinners acquire gen (invalidates L1/L2 before subsequent loads).
__device__ __forceinline__ void grid_barrier(unsigned* cnt, unsigned* gen) {
  __syncthreads();
  if (threadIdx.x == 0) {
    unsigned g = __hip_atomic_load(gen, __ATOMIC_RELAXED, __HIP_MEMORY_SCOPE_AGENT);
    unsigned a = __hip_atomic_fetch_add(cnt, 1u, __ATOMIC_ACQ_REL, __HIP_MEMORY_SCOPE_AGENT);
    if (a == 511u) {
      __hip_atomic_store(cnt, 0u, __ATOMIC_RELAXED, __HIP_MEMORY_SCOPE_AGENT);
      __hip_atomic_store(gen, g + 1u, __ATOMIC_RELEASE, __HIP_MEMORY_SCOPE_AGENT);
    } else {
      unsigned cur;
      do {
        __builtin_amdgcn_s_sleep(2);
        cur = __hip_atomic_load(gen, __ATOMIC_ACQUIRE, __HIP_MEMORY_SCOPE_AGENT);
      } while (cur == g);
    }
  }
  __syncthreads();
}

// ---------------- GEMM mainloop: C128x128 = A(128xK) * W(128xK)^T ----------------
// Round-9 verified: BK=64, double-buffered LDS (2x16KB per operand); STAGE(t+1)
// issued before compute(t) so DMA overlaps MFMA. XOR-swizzled 16B chunks:
// phys chunk (row*8 + c8) holds logical cols ((c8 ^ (row&7))*8 ..+7).
// K = 1024 fixed. 4 waves, 2x2 wave grid, 4x4 16x16x32 frags per wave.
__device__ __forceinline__ void gemm_mainloop(
    const u16* __restrict__ A, const u16* __restrict__ W,
    u16* As, u16* Bs, int tm, int tn, int w, int lane, f32x4 acc[4][4])
{
  const int K = 1024;
  const int wr = (w >> 1) * 64, wc = (w & 1) * 64;
  const int l15 = lane & 15, l4 = lane >> 4;
  const int srow = lane >> 3;
  const int scol = ((lane & 7) ^ ((lane >> 3) & 7)) * 8;

#define STAGE(k0, bf)                                                              \
  {                                                                                \
    _Pragma("unroll")                                                              \
    for (int c = 0; c < 4; ++c) {                                                  \
      int j = w * 4 + c;                                                           \
      int row = j * 8 + srow;                                                      \
      load16_to_lds(A + (size_t)(tm + row) * K + (k0) + scol,                      \
                    (char*)(As + (bf) * 8192) + j * 1024);                         \
      load16_to_lds(W + (size_t)(tn + row) * K + (k0) + scol,                      \
                    (char*)(Bs + (bf) * 8192) + j * 1024);                         \
    }                                                                              \
  }

  STAGE(0, 0);
  __syncthreads();
  for (int t = 0; t < 16; ++t) {
    if (t < 15) STAGE((t + 1) << 6, (t + 1) & 1);
    const u16* Ac = As + (t & 1) * 8192;
    const u16* Bc = Bs + (t & 1) * 8192;
#pragma unroll
    for (int kc = 0; kc < 2; ++kc) {
      short8 af[4], bfr[4];
#pragma unroll
      for (int tt = 0; tt < 4; ++tt) {
        int ra = wr + tt * 16 + l15, rb = wc + tt * 16 + l15;
        af[tt]  = *(const short8*)&Ac[ra * 64 + (((kc * 4 + l4) ^ (ra & 7)) * 8)];
        bfr[tt] = *(const short8*)&Bc[rb * 64 + (((kc * 4 + l4) ^ (rb & 7)) * 8)];
      }
#pragma unroll
      for (int rt = 0; rt < 4; ++rt)
#pragma unroll
        for (int nt = 0; nt < 4; ++nt)
          acc[rt][nt] = __builtin_amdgcn_mfma_f32_16x16x32_bf16(af[rt], bfr[nt], acc[rt][nt], 0, 0, 0);
    }
    __syncthreads();   // drains: frag ds_reads (all waves) + next buffer's DMA
  }
#undef STAGE
}

// ---------------- the fused persistent kernel ----------------
__global__ __launch_bounds__(256, 2) void mha_fused(
    const float* __restrict__ q, const float* __restrict__ k,
    const float* __restrict__ Wq, const float* __restrict__ Wk,
    const float* __restrict__ Wo, float* __restrict__ out,
    u16* __restrict__ q_b, u16* __restrict__ k_b,
    u16* __restrict__ Wq_b, u16* __restrict__ Wk_b, u16* __restrict__ Wo_b,
    u16* __restrict__ qh, u16* __restrict__ kh, u16* __restrict__ khT,
    u16* __restrict__ ao, unsigned* bar)
{
  __shared__ __align__(16) u16 smem[4 * 8192];   // 64 KB (gemm: As+Bs; flash: Ks+Kt)
  const int bid = blockIdx.x;                    // 0..511
  const int tid = threadIdx.x, w = tid >> 6, lane = tid & 63;
  const int l15 = lane & 15, l4 = lane >> 4;
  const f32x4 zero4 = {0.f, 0.f, 0.f, 0.f};
  unsigned* cnt = bar;
  unsigned* gen = bar + 1;

  // ======== stage 0: casts (q,k,Wq,Wk,Wo -> bf16), grid-strided ========
  {
    const int gsz = 512 * 256;
    const int g = bid * 256 + tid;
    for (int i = g; i < 2097152; i += gsz) { cast4(q, q_b, i); cast4(k, k_b, i); }
    for (int i = g; i < 262144; i += gsz)  { cast4(Wq, Wq_b, i); cast4(Wk, Wk_b, i); cast4(Wo, Wo_b, i); }
  }
  grid_barrier(cnt, gen);

  // ======== stage 1: Q + K projections (z = 0,1 per block) ========
  {
    const int swz = (bid & 7) * 64 + (bid >> 3);   // XCD-contiguous remap
    const int tm = (swz >> 3) * 128, tn = (swz & 7) * 128;
    const int wr = (w >> 1) * 64, wc = (w & 1) * 64;
    const int N = 1024;
    for (int z = 0; z < 2; ++z) {
      const u16* A = z ? k_b : q_b;
      const u16* W = z ? Wk_b : Wq_b;
      f32x4 acc[4][4];
      for (int i = 0; i < 4; ++i)
        for (int j = 0; j < 4; ++j) acc[i][j] = zero4;

      gemm_mainloop(A, W, smem, smem + 16384, tm, tn, w, lane, acc);

      const float scale = z ? 1.0f : 0.18033688011112042f;   // Q: 0.125*log2(e)
      u16* C = z ? kh : qh;
#pragma unroll
      for (int rt = 0; rt < 4; ++rt)
#pragma unroll
        for (int nt = 0; nt < 4; ++nt) {
          int row0 = tm + wr + rt * 16 + l4 * 4;
          int col = tn + wc + nt * 16 + l15;
          u16 vb[4];
#pragma unroll
          for (int r = 0; r < 4; ++r) vb[r] = f2bf(acc[rt][nt][r] * scale);
#pragma unroll
          for (int r = 0; r < 4; ++r)
            C[(size_t)(row0 + r) * N + col] = vb[r];
          if (z) {
            int b = row0 >> 11, t = row0 & 2047;
            int h = col >> 6, d = col & 63;
            u16x4 pack = {vb[0], vb[1], vb[2], vb[3]};
            *(u16x4*)&khT[(((size_t)(b * 16 + h) * 64 + d) << 11) + t] = pack;
          }
        }
      if (z == 0) __syncthreads();   // protect smem before z=1 restages
    }
  }
  grid_barrier(cnt, gen);

  // ======== stage 2: causal flash attention (round-2 v2 body, verified) ========
  // block -> (bh, tile pair pj & 15-pj): exactly 34 kt-iters per block.
  {
    const int T = 2048, E = 1024;
    u16* Ks = smem;            // [buf][keys x d] swizzled, 2*4096 u16
    u16* Kt = smem + 8192;     // [buf][d x keys] swizzled, 2*4096 u16
    const int xcd = bid & 7;
    const int bh = xcd * 8 + ((bid >> 3) & 7);   // 8 bh per XCD (L2 pinning)
    const int pj = bid >> 6;                     // 0..7
    const int b = bh >> 4, h = bh & 15;
    const size_t base = (size_t)b * T * E + (size_t)h * 64;
    const size_t tb = (size_t)bh * 64 * 2048;
    const int sw8 = (l4 ^ (l15 & 7)) * 8;        // swizzled in-row offset, kc=0

#define STAGEK(kt, bf)                                                             \
  {                                                                                \
    int kbase_ = (kt) * 64;                                                        \
    _Pragma("unroll")                                                              \
    for (int c = 0; c < 2; ++c) {                                                  \
      int ch = (w * 2 + c) * 64 + lane;                                            \
      int row = ch >> 3;                                                           \
      int col = ((ch & 7) ^ (row & 7)) * 8;                                        \
      load16_to_lds(kh + base + (size_t)(kbase_ + row) * E + col,                  \
                    (char*)(Ks + (bf) * 4096) + (w * 2 + c) * 1024);               \
      load16_to_lds(khT + tb + (size_t)row * 2048 + kbase_ + col,                  \
                    (char*)(Kt + (bf) * 4096) + (w * 2 + c) * 1024);               \
    }                                                                              \
  }

    for (int half = 0; half < 2; ++half) {
      const int tile = half ? (15 - pj) : pj;
      const int qbase = tile * 128;
      const int wq = qbase + w * 32;

      short8 qf[2][2];
#pragma unroll
      for (int mt = 0; mt < 2; ++mt)
#pragma unroll
        for (int kc = 0; kc < 2; ++kc)
          qf[mt][kc] = *(const short8*)&qh[base + (size_t)(wq + mt * 16 + l15) * E + kc * 32 + l4 * 8];

      f32x4 o[2][4];
      float l_i[2] = {0.f, 0.f};
#pragma unroll
      for (int mt = 0; mt < 2; ++mt)
#pragma unroll
        for (int dt = 0; dt < 4; ++dt) o[mt][dt] = zero4;

      const int nkt = tile * 2 + 2;
      STAGEK(0, 0);
      __syncthreads();
      for (int kt = 0; kt < nkt; ++kt) {
        const int kbase = kt * 64;
        if (kt + 1 < nkt) STAGEK(kt + 1, (kt + 1) & 1);
        const u16* KsC = Ks + (kt & 1) * 4096;
        const u16* KtC = Kt + (kt & 1) * 4096;

        // S^T = K Q^T : lane holds S[key = kbase+nt*16+l4*4+r][q = wq+mt*16+l15]
        f32x4 s[4][2];
#pragma unroll
        for (int nt = 0; nt < 4; ++nt) {
          s[nt][0] = zero4; s[nt][1] = zero4;
#pragma unroll
          for (int kc = 0; kc < 2; ++kc) {
            short8 kf = *(const short8*)&KsC[(nt * 16 + l15) * 64 + (sw8 ^ (kc * 32))];
            s[nt][0] = __builtin_amdgcn_mfma_f32_16x16x32_bf16(kf, qf[0][kc], s[nt][0], 0, 0, 0);
            s[nt][1] = __builtin_amdgcn_mfma_f32_16x16x32_bf16(kf, qf[1][kc], s[nt][1], 0, 0, 0);
          }
        }

        // p = 2^s (deferred norm), mask, pack to bf16, in-register transpose
        short8 pf[2][2];
#pragma unroll
        for (int mt = 0; mt < 2; ++mt) {
          unsigned pk[4][2];
          float acc = 0.f;
          const int qrow = wq + mt * 16 + l15;
          if (kbase + 63 > wq + mt * 16) {        // wave-uniform per mt
#pragma unroll
            for (int nt = 0; nt < 4; ++nt) {
              const int kk = kbase + nt * 16 + l4 * 4;
              float p0 = fexp2(s[nt][mt][0]); p0 = (kk + 0 > qrow) ? 0.f : p0;
              float p1 = fexp2(s[nt][mt][1]); p1 = (kk + 1 > qrow) ? 0.f : p1;
              float p2 = fexp2(s[nt][mt][2]); p2 = (kk + 2 > qrow) ? 0.f : p2;
              float p3 = fexp2(s[nt][mt][3]); p3 = (kk + 3 > qrow) ? 0.f : p3;
              acc += (p0 + p1) + (p2 + p3);
              pk[nt][0] = pack_bf16(p0, p1);
              pk[nt][1] = pack_bf16(p2, p3);
            }
          } else {
#pragma unroll
            for (int nt = 0; nt < 4; ++nt) {
              float p0 = fexp2(s[nt][mt][0]);
              float p1 = fexp2(s[nt][mt][1]);
              float p2 = fexp2(s[nt][mt][2]);
              float p3 = fexp2(s[nt][mt][3]);
              acc += (p0 + p1) + (p2 + p3);
              pk[nt][0] = pack_bf16(p0, p1);
              pk[nt][1] = pack_bf16(p2, p3);
            }
          }
          l_i[mt] += acc;
          // 4x4 dword transpose (lane-group l4 <-> register index)
#pragma unroll
          for (int kc = 0; kc < 2; ++kc) {
            unsigned X0 = pk[2 * kc][0], X1 = pk[2 * kc][1];
            unsigned Y0 = pk[2 * kc + 1][0], Y1 = pk[2 * kc + 1][1];
            plane32_swap(X0, Y0);
            plane32_swap(X1, Y1);
            plane16_swap(X0, Y0);
            plane16_swap(X1, Y1);
            union { unsigned u[4]; short8 s8; } cvt;
            cvt.u[0] = X0; cvt.u[1] = X1; cvt.u[2] = Y0; cvt.u[3] = Y1;
            pf[mt][kc] = cvt.s8;
          }
        }

        // O += P * V  (V = K; B-frags from Kt rows, shared across m-frags)
#pragma unroll
        for (int kc = 0; kc < 2; ++kc) {
#pragma unroll
          for (int dt = 0; dt < 4; ++dt) {
            short8 vfr = *(const short8*)&KtC[(dt * 16 + l15) * 64 + (sw8 ^ (kc * 32))];
            o[0][dt] = __builtin_amdgcn_mfma_f32_16x16x32_bf16(pf[0][kc], vfr, o[0][dt], 0, 0, 0);
            o[1][dt] = __builtin_amdgcn_mfma_f32_16x16x32_bf16(pf[1][kc], vfr, o[1][dt], 0, 0, 0);
          }
        }
        __syncthreads();   // publishes next buffer; protects current buffer reads
      }

      // deferred l-reduction + normalize + store
#pragma unroll
      for (int mt = 0; mt < 2; ++mt) {
        float lt = l_i[mt];
        lt += __shfl_xor(lt, 16);
        lt += __shfl_xor(lt, 32);
        float inv[4];
#pragma unroll
        for (int r = 0; r < 4; ++r) inv[r] = frcp(__shfl(lt, l4 * 4 + r));
#pragma unroll
        for (int dt = 0; dt < 4; ++dt)
#pragma unroll
          for (int r = 0; r < 4; ++r) {
            int row = wq + mt * 16 + l4 * 4 + r;
            ao[base + (size_t)row * E + dt * 16 + l15] = f2bf(o[mt][dt][r] * inv[r]);
          }
      }
      if (half == 0) __syncthreads();   // protect smem before second tile restages
    }
#undef STAGEK
  }
  grid_barrier(cnt, gen);

  // ======== stage 3: O projection (f32 out) ========
  {
    const int swz = (bid & 7) * 64 + (bid >> 3);   // XCD-contiguous remap
    const int tm = (swz >> 3) * 128, tn = (swz & 7) * 128;
    const int wr = (w >> 1) * 64, wc = (w & 1) * 64;
    const int N = 1024;
    f32x4 acc[4][4];
    for (int i = 0; i < 4; ++i)
      for (int j = 0; j < 4; ++j) acc[i][j] = zero4;

    gemm_mainloop(ao, Wo_b, smem, smem + 16384, tm, tn, w, lane, acc);

#pragma unroll
    for (int rt = 0; rt < 4; ++rt)
#pragma unroll
      for (int nt = 0; nt < 4; ++nt) {
        int row0 = tm + wr + rt * 16 + l4 * 4;
        int col = tn + wc + nt * 16 + l15;
#pragma unroll
        for (int r = 0; r < 4; ++r)
          out[(size_t)(row0 + r) * N + col] = acc[rt][nt][r];
      }
  }
}

extern "C" void kernel_launch(void* const* d_in, const int* in_sizes, int n_in,
                              void* d_out, int out_size, void* d_ws, size_t ws_size,
                              hipStream_t stream) {
  (void)in_sizes; (void)n_in; (void)out_size; (void)ws_size;
  const float* q  = (const float*)d_in[0];
  const float* k  = (const float*)d_in[1];
  // d_in[2] = v : unused (share_kv=True)
  const float* Wq = (const float*)d_in[3];
  const float* Wk = (const float*)d_in[4];
  const float* Wo = (const float*)d_in[5];
  float* out = (float*)d_out;

  const size_t nBTE = (size_t)4 * 2048 * 1024;   // 8388608
  const size_t nEE  = (size_t)1024 * 1024;

  char* p = (char*)d_ws;
  u16* q_b  = (u16*)p; p += nBTE * 2;
  u16* k_b  = (u16*)p; p += nBTE * 2;
  u16* Wq_b = (u16*)p; p += nEE * 2;
  u16* Wk_b = (u16*)p; p += nEE * 2;
  u16* Wo_b = (u16*)p; p += nEE * 2;
  u16* qh   = (u16*)p; p += nBTE * 2;
  u16* kh   = (u16*)p; p += nBTE * 2;
  u16* khT  = (u16*)p; p += nBTE * 2;
  unsigned* bar = (unsigned*)p;                  // barrier state (cnt, gen)
  u16* ao   = q_b;   // alias: q_b dead after stage 1; flash writes ao in stage 2

  hipMemsetAsync(bar, 0, 64, stream);            // zero barrier state (capturable)

  mha_fused<<<dim3(512), dim3(256), 0, stream>>>(
      q, k, Wq, Wk, Wo, out,
      q_b, k_b, Wq_b, Wk_b, Wo_b, qh, kh, khT, ao, bar);
}

// Round 14
// 251.704 us; speedup vs baseline: 2.0077x; 2.0077x over previous
//
#include <hip/hip_runtime.h>
#include <cstdint>

// MHA fused: qh = (q@Wq^T)*0.125*log2e, kh = k@Wk^T (+khT transposed copy),
// flash-causal-attn(qh,kh,V=kh) with deferred-normalization softmax, out = ao@Wo^T.
// B=4 T=2048 E=1024 H=16 D=64. v input (d_in[2]) DEAD (share_kv=True).
//
// Round 14: round-9 baseline (verified 255us; fusion abandoned — round-13
// showed the ~100us overhead is FIXED harness cost, not per-launch) with ONE
// change: gemm_qk ported to a 256^2-tile phase-split schedule (T3+T4+T5):
// 512 thr / 8 waves, BK=64, full-tile double buffer (128KB dynamic LDS),
// counted s_waitcnt vmcnt(8) across raw s_barriers (never drain in-loop),
// 4 compute phases per K-tile with setprio(1) around each 16-MFMA cluster.
// cast_all / flash_attn / gemm_o byte-identical to round-9.

typedef unsigned short u16;
typedef __attribute__((ext_vector_type(8))) short short8;
typedef __attribute__((ext_vector_type(4))) float f32x4;
typedef __attribute__((ext_vector_type(4))) unsigned short u16x4;
typedef __attribute__((ext_vector_type(2))) unsigned int u32x2;

__device__ __forceinline__ u16 f2bf(float x) {
  unsigned int u = __float_as_uint(x);
  u += 0x7fffu + ((u >> 16) & 1u);   // RNE
  return (u16)(u >> 16);
}

__device__ __forceinline__ float fexp2(float x) {
#if __has_builtin(__builtin_amdgcn_exp2f)
  return __builtin_amdgcn_exp2f(x);
#else
  return __expf(x * 0.69314718056f);
#endif
}

__device__ __forceinline__ float frcp(float x) {
#if __has_builtin(__builtin_amdgcn_rcpf)
  return __builtin_amdgcn_rcpf(x);
#else
  return 1.0f / x;
#endif
}

__device__ __forceinline__ void load16_to_lds(const void* g, void* lds_base_uniform) {
  // HW writes LDS at wave-uniform base + lane*16; g is per-lane.
  __builtin_amdgcn_global_load_lds(
      (const __attribute__((address_space(1))) void*)g,
      (__attribute__((address_space(3))) void*)lds_base_uniform,
      16, 0, 0);
}

// pack two f32 -> one dword of 2 truncated bf16 (lo = a, hi = b)
__device__ __forceinline__ unsigned pack_bf16(float a, float b) {
  return __builtin_amdgcn_perm(__float_as_uint(b), __float_as_uint(a), 0x07060302u);
}

// swap halves: {x,y} -> x' = {x.lo32lanes, y.lo32lanes}, y' = {x.hi, y.hi}
__device__ __forceinline__ void plane32_swap(unsigned &x, unsigned &y) {
#if __has_builtin(__builtin_amdgcn_permlane32_swap)
  u32x2 r = __builtin_amdgcn_permlane32_swap(x, y, false, false);
  x = r.x; y = r.y;
#else
  asm volatile("v_permlane32_swap_b32 %0, %1" : "+v"(x), "+v"(y));
#endif
}

__device__ __forceinline__ void plane16_swap(unsigned &x, unsigned &y) {
#if __has_builtin(__builtin_amdgcn_permlane16_swap)
  u32x2 r = __builtin_amdgcn_permlane16_swap(x, y, false, false);
  x = r.x; y = r.y;
#else
  asm volatile("v_permlane16_swap_b32 %0, %1" : "+v"(x), "+v"(y));
#endif
}

// ---------------- all casts, one dispatch ----------------
// float4-group index space: q[0,2097152) k[..4194304) Wq[..4456448)
// Wk[..4718592) Wo[..4980736). grid 19456 x 256.
__global__ void cast_all(const float* __restrict__ q, const float* __restrict__ k,
                         const float* __restrict__ Wq, const float* __restrict__ Wk,
                         const float* __restrict__ Wo,
                         u16* __restrict__ qb, u16* __restrict__ kb,
                         u16* __restrict__ Wqb, u16* __restrict__ Wkb,
                         u16* __restrict__ Wob) {
  int i = blockIdx.x * 256 + threadIdx.x;
  const float* s; u16* d; int off;
  if (i < 2097152)      { s = q;  d = qb;  off = i; }
  else if (i < 4194304) { s = k;  d = kb;  off = i - 2097152; }
  else if (i < 4456448) { s = Wq; d = Wqb; off = i - 4194304; }
  else if (i < 4718592) { s = Wk; d = Wkb; off = i - 4456448; }
  else                  { s = Wo; d = Wob; off = i - 4718592; }
  float4 f = ((const float4*)s)[off];
  uint2 p;
  p.x = (unsigned int)f2bf(f.x) | ((unsigned int)f2bf(f.y) << 16);
  p.y = (unsigned int)f2bf(f.z) | ((unsigned int)f2bf(f.w) << 16);
  ((uint2*)d)[off] = p;
}

// ---------------- GEMM mainloop (128^2, round-9): for gemm_o ----------------
__device__ __forceinline__ void gemm_mainloop(
    const u16* __restrict__ A, const u16* __restrict__ W,
    u16* As, u16* Bs, int tm, int tn, int w, int lane, f32x4 acc[4][4])
{
  const int K = 1024;
  const int wr = (w >> 1) * 64, wc = (w & 1) * 64;
  const int l15 = lane & 15, l4 = lane >> 4;
  const int srow = lane >> 3;
  const int scol = ((lane & 7) ^ ((lane >> 3) & 7)) * 8;

#define STAGE(k0, bf)                                                              \
  {                                                                                \
    _Pragma("unroll")                                                              \
    for (int c = 0; c < 4; ++c) {                                                  \
      int j = w * 4 + c;                                                           \
      int row = j * 8 + srow;                                                      \
      load16_to_lds(A + (size_t)(tm + row) * K + (k0) + scol,                      \
                    (char*)(As + (bf) * 8192) + j * 1024);                         \
      load16_to_lds(W + (size_t)(tn + row) * K + (k0) + scol,                      \
                    (char*)(Bs + (bf) * 8192) + j * 1024);                         \
    }                                                                              \
  }

  STAGE(0, 0);
  __syncthreads();
  for (int t = 0; t < 16; ++t) {
    if (t < 15) STAGE((t + 1) << 6, (t + 1) & 1);
    const u16* Ac = As + (t & 1) * 8192;
    const u16* Bc = Bs + (t & 1) * 8192;
#pragma unroll
    for (int kc = 0; kc < 2; ++kc) {
      short8 af[4], bfr[4];
#pragma unroll
      for (int tt = 0; tt < 4; ++tt) {
        int ra = wr + tt * 16 + l15, rb = wc + tt * 16 + l15;
        af[tt]  = *(const short8*)&Ac[ra * 64 + (((kc * 4 + l4) ^ (ra & 7)) * 8)];
        bfr[tt] = *(const short8*)&Bc[rb * 64 + (((kc * 4 + l4) ^ (rb & 7)) * 8)];
      }
#pragma unroll
      for (int rt = 0; rt < 4; ++rt)
#pragma unroll
        for (int nt = 0; nt < 4; ++nt)
          acc[rt][nt] = __builtin_amdgcn_mfma_f32_16x16x32_bf16(af[rt], bfr[nt], acc[rt][nt], 0, 0, 0);
    }
    __syncthreads();   // drains: frag ds_reads (all waves) + next buffer's DMA
  }
#undef STAGE
}

// ---------------- Q + K projections: 256^2 tile, phase-split, counted vmcnt -------
// 512 thr = 8 waves (2M x 4N): wave owns 128x64 of C (8 m-frags x 4 n-frags).
// LDS (dynamic 128KB): As[2][256][64] + Bs[2][256][64] bf16, chunk-XOR swizzle
// (phys 16B chunk c of row r holds logical cols ((c ^ (r&7))*8..+7)).
// K-loop per tile t: issue STAGE(t+1) -> vmcnt(8) (t+1's 8 loads stay in
// flight) -> raw s_barrier -> 4 phases {8 ds_read_b128, setprio(1),
// 16 MFMA, setprio(0), s_barrier}. No vmcnt(0) until the last tile.
// Block mapping: gid swizzled so each XCD serves one z with 8 m-tiles x 4
// n-tiles (A K-slices + W K-slices stay L2-resident).
__global__ __launch_bounds__(512, 2) void gemm_qk(
    const u16* __restrict__ qb, const u16* __restrict__ Wq,
    const u16* __restrict__ kb, const u16* __restrict__ Wk,
    u16* __restrict__ qh, u16* __restrict__ kh, u16* __restrict__ khT)
{
  extern __shared__ __align__(16) u16 smem[];
  u16* As = smem;              // [2][256*64]
  u16* Bs = smem + 32768;      // [2][256*64]
  const int tid = threadIdx.x, w = tid >> 6, lane = tid & 63;
  const int l15 = lane & 15, l4 = lane >> 4;
  const int gid = blockIdx.x + 4 * (blockIdx.y + 32 * blockIdx.z);  // 0..255
  const int sw = (gid & 7) * 32 + (gid >> 3);                        // XCD-contig
  const int z = sw >> 7;                                             // XCDs 0-3: z=0
  const int r = sw & 127;
  const int tm = (r >> 2) * 256, tn = (r & 3) * 256;
  const int wr = (w >> 2) * 128, wc = (w & 3) * 64;
  const int K = 1024, N = 1024;
  const u16* A = z ? kb : qb;
  const u16* W = z ? Wk : Wq;

  f32x4 zero4 = {0.f, 0.f, 0.f, 0.f};
  f32x4 acc[8][4];
#pragma unroll
  for (int i = 0; i < 8; ++i)
#pragma unroll
    for (int j = 0; j < 4; ++j) acc[i][j] = zero4;

  // stage one full 256x64 K-tile of A and of W: 4+4 loads/thread.
#define STAGE2(k0, bf)                                                             \
  {                                                                                \
    _Pragma("unroll")                                                              \
    for (int c = 0; c < 4; ++c) {                                                  \
      int g = c * 512 + tid;                                                       \
      int row = g >> 3;                                                            \
      int col = ((g & 7) ^ (row & 7)) * 8;                                         \
      load16_to_lds(A + (size_t)(tm + row) * K + (k0) + col,                       \
                    (char*)(As + (bf) * 16384) + (c * 512 + w * 64) * 16);         \
      load16_to_lds(W + (size_t)(tn + row) * K + (k0) + col,                       \
                    (char*)(Bs + (bf) * 16384) + (c * 512 + w * 64) * 16);         \
    }                                                                              \
  }

  // one compute phase: m-half mh, k-chunk kc; reload B-frags when mh==0.
#define PHASE2(mh, kc)                                                             \
  {                                                                                \
    short8 af[4];                                                                  \
    _Pragma("unroll")                                                              \
    for (int i = 0; i < 4; ++i) {                                                  \
      int ra = wr + ((mh) * 4 + i) * 16 + l15;                                     \
      af[i] = *(const short8*)&Ab[ra * 64 + ((((kc) * 4 + l4) ^ (ra & 7)) * 8)];   \
    }                                                                              \
    if ((mh) == 0) {                                                               \
      _Pragma("unroll")                                                            \
      for (int n = 0; n < 4; ++n) {                                                \
        int rb = wc + n * 16 + l15;                                                \
        bfr[n] = *(const short8*)&Bb[rb * 64 + ((((kc) * 4 + l4) ^ (rb & 7)) * 8)];\
      }                                                                            \
    }                                                                              \
    __builtin_amdgcn_s_setprio(1);                                                 \
    _Pragma("unroll")                                                              \
    for (int i = 0; i < 4; ++i)                                                    \
      _Pragma("unroll")                                                            \
      for (int n = 0; n < 4; ++n)                                                  \
        acc[(mh) * 4 + i][n] =                                                     \
            __builtin_amdgcn_mfma_f32_16x16x32_bf16(af[i], bfr[n],                 \
                                                    acc[(mh) * 4 + i][n], 0, 0, 0);\
    __builtin_amdgcn_s_setprio(0);                                                 \
    __builtin_amdgcn_s_barrier();                                                  \
    __builtin_amdgcn_sched_barrier(0);                                             \
  }

  STAGE2(0, 0);
  for (int t = 0; t < 16; ++t) {
    if (t < 15) {
      STAGE2((t + 1) << 6, (t + 1) & 1);
      asm volatile("s_waitcnt vmcnt(8)" ::: "memory");  // t's 8 loads done; t+1's fly
    } else {
      asm volatile("s_waitcnt vmcnt(0)" ::: "memory");
    }
    __builtin_amdgcn_s_barrier();          // all waves' staged data visible
    __builtin_amdgcn_sched_barrier(0);
    const u16* Ab = As + (t & 1) * 16384;
    const u16* Bb = Bs + (t & 1) * 16384;
    short8 bfr[4];
    PHASE2(0, 0);
    PHASE2(1, 0);
    PHASE2(0, 1);
    PHASE2(1, 1);   // last phase's s_barrier = reads-done fence for next STAGE2
  }
#undef STAGE2
#undef PHASE2

  const float scale = z ? 1.0f : 0.18033688011112042f;   // Q: 0.125*log2(e)
  u16* C = z ? kh : qh;
#pragma unroll
  for (int rt = 0; rt < 8; ++rt)
#pragma unroll
    for (int nt = 0; nt < 4; ++nt) {
      int row0 = tm + wr + rt * 16 + l4 * 4;
      int col = tn + wc + nt * 16 + l15;
      u16 vb[4];
#pragma unroll
      for (int rr = 0; rr < 4; ++rr) vb[rr] = f2bf(acc[rt][nt][rr] * scale);
#pragma unroll
      for (int rr = 0; rr < 4; ++rr)
        C[(size_t)(row0 + rr) * N + col] = vb[rr];
      if (z) {
        int b = row0 >> 11, tt = row0 & 2047;
        int h = col >> 6, d = col & 63;
        u16x4 pack = {vb[0], vb[1], vb[2], vb[3]};
        *(u16x4*)&khT[(((size_t)(b * 16 + h) * 64 + d) << 11) + tt] = pack;
      }
    }
}

// ---------------- O projection, f32 out (round-9, 128^2) ----------------
__global__ __launch_bounds__(256) void gemm_o(
    const u16* __restrict__ A, const u16* __restrict__ W, float* __restrict__ out)
{
  __shared__ __align__(16) u16 As[2 * 8192];
  __shared__ __align__(16) u16 Bs[2 * 8192];
  const int tid = threadIdx.x, w = tid >> 6, lane = tid & 63;
  const int l15 = lane & 15, l4 = lane >> 4;
  const int lin = blockIdx.x + 8 * blockIdx.y;   // 0..511
  const int swz = (lin & 7) * 64 + (lin >> 3);   // XCD-contiguous remap
  const int tm = (swz >> 3) * 128, tn = (swz & 7) * 128;
  const int wr = (w >> 1) * 64, wc = (w & 1) * 64;
  const int N = 1024;

  f32x4 zero4 = {0.f, 0.f, 0.f, 0.f};
  f32x4 acc[4][4];
  for (int i = 0; i < 4; ++i)
    for (int j = 0; j < 4; ++j) acc[i][j] = zero4;

  gemm_mainloop(A, W, As, Bs, tm, tn, w, lane, acc);

#pragma unroll
  for (int rt = 0; rt < 4; ++rt)
#pragma unroll
    for (int nt = 0; nt < 4; ++nt) {
      int row0 = tm + wr + rt * 16 + l4 * 4;
      int col = tn + wc + nt * 16 + l15;
#pragma unroll
      for (int r = 0; r < 4; ++r)
        out[(size_t)(row0 + r) * N + col] = acc[rt][nt][r];
    }
}

// ---------------- causal flash attention, V = K, deferred-norm ----------------
// EXACT round-2 v2: grid 1024 (one 128-row Q-tile per block, big tiles first,
// XCD-swizzled), 4 waves x 32 q-rows, Ks/Kt double-buffered (2x8KB each),
// ONE barrier per iter. Swapped QK^T; P packed (v_perm) + permlane-transposed
// to PV A-frags in-register; VALU l-sum + epilogue shuffles; branch-free body.
__global__ __launch_bounds__(256, 4) void flash_attn(
    const u16* __restrict__ qh, const u16* __restrict__ kh,
    const u16* __restrict__ khT, u16* __restrict__ ao)
{
  const int T = 2048, E = 1024;
  __shared__ __align__(16) u16 Ks[2 * 4096];     // [buf][keys x d] swizzled
  __shared__ __align__(16) u16 Kt[2 * 4096];     // [buf][d x keys] swizzled

  const int L = blockIdx.x;                      // 0..1023
  const int xcd = L & 7;
  const int li = L >> 3;                         // 0..127
  const int tile = 15 - (li >> 3);               // big tiles first
  const int bh = xcd * 8 + (li & 7);             // 8 bh per XCD
  const int b = bh >> 4, h = bh & 15;
  const size_t base = (size_t)b * T * E + (size_t)h * 64;
  const size_t tb = (size_t)bh * 64 * 2048;
  const int tid = threadIdx.x, w = tid >> 6, lane = tid & 63;
  const int l15 = lane & 15, l4 = lane >> 4;
  const int sw8 = (l4 ^ (l15 & 7)) * 8;          // swizzled in-row offset, kc=0
  f32x4 zero4 = {0.f, 0.f, 0.f, 0.f};

#define STAGEK(kt, bf)                                                             \
  {                                                                                \
    int kbase_ = (kt) * 64;                                                        \
    _Pragma("unroll")                                                              \
    for (int c = 0; c < 2; ++c) {                                                  \
      int ch = (w * 2 + c) * 64 + lane;                                            \
      int row = ch >> 3;                                                           \
      int col = ((ch & 7) ^ (row & 7)) * 8;                                        \
      load16_to_lds(kh + base + (size_t)(kbase_ + row) * E + col,                  \
                    (char*)(Ks + (bf) * 4096) + (w * 2 + c) * 1024);               \
      load16_to_lds(khT + tb + (size_t)row * 2048 + kbase_ + col,                  \
                    (char*)(Kt + (bf) * 4096) + (w * 2 + c) * 1024);               \
    }                                                                              \
  }

  const int qbase = tile * 128;
  const int wq = qbase + w * 32;

  short8 qf[2][2];
#pragma unroll
  for (int mt = 0; mt < 2; ++mt)
#pragma unroll
    for (int kc = 0; kc < 2; ++kc)
      qf[mt][kc] = *(const short8*)&qh[base + (size_t)(wq + mt * 16 + l15) * E + kc * 32 + l4 * 8];

  f32x4 o[2][4];
  float l_i[2] = {0.f, 0.f};
#pragma unroll
  for (int mt = 0; mt < 2; ++mt)
#pragma unroll
    for (int dt = 0; dt < 4; ++dt) o[mt][dt] = zero4;

  const int nkt = tile * 2 + 2;
  STAGEK(0, 0);
  __syncthreads();
  for (int kt = 0; kt < nkt; ++kt) {
    const int kbase = kt * 64;
    if (kt + 1 < nkt) STAGEK(kt + 1, (kt + 1) & 1);
    const u16* KsC = Ks + (kt & 1) * 4096;
    const u16* KtC = Kt + (kt & 1) * 4096;

    // S^T = K Q^T : lane holds S[key = kbase+nt*16+l4*4+r][q = wq+mt*16+l15]
    f32x4 s[4][2];
#pragma unroll
    for (int nt = 0; nt < 4; ++nt) {
      s[nt][0] = zero4; s[nt][1] = zero4;
#pragma unroll
      for (int kc = 0; kc < 2; ++kc) {
        short8 kf = *(const short8*)&KsC[(nt * 16 + l15) * 64 + (sw8 ^ (kc * 32))];
        s[nt][0] = __builtin_amdgcn_mfma_f32_16x16x32_bf16(kf, qf[0][kc], s[nt][0], 0, 0, 0);
        s[nt][1] = __builtin_amdgcn_mfma_f32_16x16x32_bf16(kf, qf[1][kc], s[nt][1], 0, 0, 0);
      }
    }

    // p = 2^s (deferred norm), mask, pack to bf16, in-register transpose
    // to PV A-frags: dest lane l4' holds keys kc*32 + l4'*8..+7 for q = l15.
    short8 pf[2][2];
#pragma unroll
    for (int mt = 0; mt < 2; ++mt) {
      unsigned pk[4][2];                          // [nt][dword-pair], keys l4*4+{01,23}
      float acc = 0.f;
      const int qrow = wq + mt * 16 + l15;
      if (kbase + 63 > wq + mt * 16) {            // wave-uniform per mt
#pragma unroll
        for (int nt = 0; nt < 4; ++nt) {
          const int kk = kbase + nt * 16 + l4 * 4;
          float p0 = fexp2(s[nt][mt][0]); p0 = (kk + 0 > qrow) ? 0.f : p0;
          float p1 = fexp2(s[nt][mt][1]); p1 = (kk + 1 > qrow) ? 0.f : p1;
          float p2 = fexp2(s[nt][mt][2]); p2 = (kk + 2 > qrow) ? 0.f : p2;
          float p3 = fexp2(s[nt][mt][3]); p3 = (kk + 3 > qrow) ? 0.f : p3;
          acc += (p0 + p1) + (p2 + p3);
          pk[nt][0] = pack_bf16(p0, p1);
          pk[nt][1] = pack_bf16(p2, p3);
        }
      } else {
#pragma unroll
        for (int nt = 0; nt < 4; ++nt) {
          float p0 = fexp2(s[nt][mt][0]);
          float p1 = fexp2(s[nt][mt][1]);
          float p2 = fexp2(s[nt][mt][2]);
          float p3 = fexp2(s[nt][mt][3]);
          acc += (p0 + p1) + (p2 + p3);
          pk[nt][0] = pack_bf16(p0, p1);
          pk[nt][1] = pack_bf16(p2, p3);
        }
      }
      l_i[mt] += acc;
      // 4x4 dword transpose over (lane-group l4, register j):
      // swap32: reg-index <-> lane-bit5; swap16: reg-index <-> lane-bit4.
#pragma unroll
      for (int kc = 0; kc < 2; ++kc) {
        unsigned X0 = pk[2 * kc][0], X1 = pk[2 * kc][1];
        unsigned Y0 = pk[2 * kc + 1][0], Y1 = pk[2 * kc + 1][1];
        plane32_swap(X0, Y0);
        plane32_swap(X1, Y1);
        plane16_swap(X0, Y0);
        plane16_swap(X1, Y1);
        union { unsigned u[4]; short8 s8; } cvt;
        cvt.u[0] = X0; cvt.u[1] = X1; cvt.u[2] = Y0; cvt.u[3] = Y1;
        pf[mt][kc] = cvt.s8;
      }
    }

    // O += P * V  (V = K; B-frags from Kt rows, shared across m-frags)
#pragma unroll
    for (int kc = 0; kc < 2; ++kc) {
#pragma unroll
      for (int dt = 0; dt < 4; ++dt) {
        short8 vfr = *(const short8*)&KtC[(dt * 16 + l15) * 64 + (sw8 ^ (kc * 32))];
        o[0][dt] = __builtin_amdgcn_mfma_f32_16x16x32_bf16(pf[0][kc], vfr, o[0][dt], 0, 0, 0);
        o[1][dt] = __builtin_amdgcn_mfma_f32_16x16x32_bf16(pf[1][kc], vfr, o[1][dt], 0, 0, 0);
      }
    }
    __syncthreads();   // publishes next buffer; protects current buffer reads
  }

  // deferred l-reduction + normalize + store
#pragma unroll
  for (int mt = 0; mt < 2; ++mt) {
    float lt = l_i[mt];
    lt += __shfl_xor(lt, 16);
    lt += __shfl_xor(lt, 32);            // lt = full key-sum for q = wq+mt*16+l15
    float inv[4];
#pragma unroll
    for (int r = 0; r < 4; ++r) inv[r] = frcp(__shfl(lt, l4 * 4 + r));
#pragma unroll
    for (int dt = 0; dt < 4; ++dt)
#pragma unroll
      for (int r = 0; r < 4; ++r) {
        int row = wq + mt * 16 + l4 * 4 + r;
        ao[base + (size_t)row * E + dt * 16 + l15] = f2bf(o[mt][dt][r] * inv[r]);
      }
  }
#undef STAGEK
}

extern "C" void kernel_launch(void* const* d_in, const int* in_sizes, int n_in,
                              void* d_out, int out_size, void* d_ws, size_t ws_size,
                              hipStream_t stream) {
  (void)in_sizes; (void)n_in; (void)out_size; (void)ws_size;
  const float* q  = (const float*)d_in[0];
  const float* k  = (const float*)d_in[1];
  // d_in[2] = v : unused (share_kv=True)
  const float* Wq = (const float*)d_in[3];
  const float* Wk = (const float*)d_in[4];
  const float* Wo = (const float*)d_in[5];
  float* out = (float*)d_out;

  const size_t nBTE = (size_t)4 * 2048 * 1024;   // 8388608
  const size_t nEE  = (size_t)1024 * 1024;

  char* p = (char*)d_ws;
  u16* q_b  = (u16*)p; p += nBTE * 2;
  u16* k_b  = (u16*)p; p += nBTE * 2;
  u16* Wq_b = (u16*)p; p += nEE * 2;
  u16* Wk_b = (u16*)p; p += nEE * 2;
  u16* Wo_b = (u16*)p; p += nEE * 2;
  u16* qh   = (u16*)p; p += nBTE * 2;
  u16* kh   = (u16*)p; p += nBTE * 2;
  u16* khT  = (u16*)p; p += nBTE * 2;
  u16* ao   = q_b;   // alias: q_b dead after Q-GEMM; flash writes ao after that

  static bool attr_set = false;
  if (!attr_set) {
    hipFuncSetAttribute(reinterpret_cast<const void*>(gemm_qk),
                        hipFuncAttributeMaxDynamicSharedMemorySize, 131072);
    attr_set = true;
  }

  cast_all<<<dim3(19456), 256, 0, stream>>>(q, k, Wq, Wk, Wo,
                                            q_b, k_b, Wq_b, Wk_b, Wo_b);

  gemm_qk<<<dim3(4, 32, 2), 512, 131072, stream>>>(q_b, Wq_b, k_b, Wk_b, qh, kh, khT);

  flash_attn<<<dim3(1024), 256, 0, stream>>>(qh, kh, khT, ao);

  gemm_o<<<dim3(8, 64), 256, 0, stream>>>(ao, Wo_b, out);
}